// Round 3
// baseline (158.626 us; speedup 1.0000x reference)
//
#include <hip/hip_runtime.h>
#include <stdint.h>
#include <math.h>

#define D_DIM 512
#define H_DIM 256
#define E_NUM 10
#define ROWS_PB 128          // rows per block (256 threads, 2 threads/row)
#define NSTEP 16             // steps; each stages 32 d-cols (16 per half) x 128 rows

// ---------- precompute: packed weights pk[d/4][e][gate4|sim4] + bias_g ----------
__global__ __launch_bounds__(256) void pre_wg(const float* __restrict__ Wp,
                                              const float* __restrict__ bp,
                                              const float* __restrict__ emb,
                                              float* __restrict__ pk,
                                              float* __restrict__ bg) {
  int gid = blockIdx.x * 256 + threadIdx.x;
  if (gid < E_NUM * D_DIM) {
    int d = gid / E_NUM;
    int e = gid - d * E_NUM;
    const float* wr = Wp + (size_t)d * H_DIM;
    const float* er = emb + (size_t)e * H_DIM;
    float s0 = 0.f, s1 = 0.f, s2 = 0.f, s3 = 0.f;
#pragma unroll 4
    for (int h = 0; h < H_DIM; h += 4) {
      float4 a = *(const float4*)(wr + h);
      float4 b = *(const float4*)(er + h);
      s0 = fmaf(a.x, b.x, s0); s1 = fmaf(a.y, b.y, s1);
      s2 = fmaf(a.z, b.z, s2); s3 = fmaf(a.w, b.w, s3);
    }
    pk[(size_t)(d >> 2) * 80 + e * 8 + (d & 3)] = ((s0 + s1) + (s2 + s3)) * 0.0625f;
  } else if (gid < E_NUM * D_DIM + E_NUM) {
    int e = gid - E_NUM * D_DIM;
    const float* er = emb + (size_t)e * H_DIM;
    float s = 0.f;
    for (int h = 0; h < H_DIM; ++h) s = fmaf(bp[h], er[h], s);
    bg[e] = s * 0.0625f;
  }
}

// ---------- precompute: normalized expert rows into pk sim slots + trust*stale ----------
__global__ __launch_bounds__(64) void pre_en(const float* __restrict__ ef,
                                             const float* __restrict__ trust,
                                             const float* __restrict__ dtv,
                                             float* __restrict__ pk,
                                             float* __restrict__ cf) {
  int e = blockIdx.x, l = threadIdx.x;
  const float* row = ef + (size_t)e * D_DIM;
  float s = 0.f;
#pragma unroll
  for (int j = 0; j < D_DIM / 64; ++j) { float v = row[l + 64 * j]; s = fmaf(v, v, s); }
#pragma unroll
  for (int o = 32; o; o >>= 1) s += __shfl_xor(s, o, 64);
  float inv = 1.f / fmaxf(sqrtf(s), 1e-8f);
#pragma unroll
  for (int j = 0; j < D_DIM / 64; ++j) {
    int d = l + 64 * j;
    pk[(size_t)(d >> 2) * 80 + e * 8 + 4 + (d & 3)] = row[d] * inv;
  }
  if (l == 0) cf[e] = trust[e] * expf(-0.001f * dtv[e]);
}

// ---------- main: 2 threads/row, 4-deep gload_lds pipeline, counted vmcnt ----------
__global__ __launch_bounds__(256, 2) void router_main(
    const float* __restrict__ feat, const float* __restrict__ pk,
    const float* __restrict__ cf, const float* __restrict__ bg,
    float* __restrict__ out, int B) {
  __shared__ float lds[4][ROWS_PB * 32];
  const int t = threadIdx.x;
  const int l = t & 63;
  const int w = __builtin_amdgcn_readfirstlane(t >> 6);  // wave id 0..3
  const int h = __builtin_amdgcn_readfirstlane(t >> 7);  // D-half 0..1
  const int p = t & 127;                                 // row within block
  const size_t r0 = (size_t)blockIdx.x * ROWS_PB;

  // staging: wave w stages rows w*8+(l>>3)+32j; lane's global quad is XOR-swizzled
  // so the LINEAR gload_lds dest realizes the swizzled LDS layout.
  const int sr = w * 8 + (l >> 3);
  const int qg = (l & 7) ^ (l >> 3);
  const float* gbase = feat + (r0 + sr) * (size_t)D_DIM + ((qg >> 2) * 256 + (qg & 3) * 4);
  const int ldsbase = (w * 8) * 32;

  float gacc[E_NUM], sacc[E_NUM], nrm = 0.f;
#pragma unroll
  for (int e = 0; e < E_NUM; ++e) { gacc[e] = 0.f; sacc[e] = 0.f; }

  auto STAGE = [&](int buf, int c) {
#pragma unroll
    for (int j = 0; j < 4; ++j) {
      __builtin_amdgcn_global_load_lds(
          (const __attribute__((address_space(1))) uint32_t*)(gbase + (size_t)j * 32 * D_DIM + c * 16),
          (__attribute__((address_space(3))) uint32_t*)&lds[buf][ldsbase + j * 1024],
          16, 0, 0);
    }
  };

  auto COMPUTE = [&](int buf, int c) {
    const int wboff = __builtin_amdgcn_readfirstlane((h * 64 + c * 4) * 80);
    const float* wb = pk + wboff;  // wave-uniform -> s_load
#pragma unroll
    for (int q = 0; q < 4; ++q) {
      const int slot = ((h << 2) + q) ^ (p & 7);
      float4 fv = *(const float4*)&lds[buf][p * 32 + slot * 4];
      const float* qb = wb + q * 80;
#pragma unroll
      for (int e = 0; e < E_NUM; ++e) {
        float4 wv = *(const float4*)(qb + e * 8);
        float4 sv = *(const float4*)(qb + e * 8 + 4);
        float a = gacc[e];
        a = fmaf(fv.x, wv.x, a); a = fmaf(fv.y, wv.y, a);
        a = fmaf(fv.z, wv.z, a); a = fmaf(fv.w, wv.w, a);
        gacc[e] = a;
        float b2 = sacc[e];
        b2 = fmaf(fv.x, sv.x, b2); b2 = fmaf(fv.y, sv.y, b2);
        b2 = fmaf(fv.z, sv.z, b2); b2 = fmaf(fv.w, sv.w, b2);
        sacc[e] = b2;
      }
      nrm = fmaf(fv.x, fv.x, nrm); nrm = fmaf(fv.y, fv.y, nrm);
      nrm = fmaf(fv.z, fv.z, nrm); nrm = fmaf(fv.w, fv.w, nrm);
    }
  };

  // prologue: fill 3 buffers (12 loads in flight)
  STAGE(0, 0); STAGE(1, 1); STAGE(2, 2);

#pragma unroll 1
  for (int c = 0; c < NSTEP - 3; ++c) {
    // step c's 4 loads are the oldest; keep 8 (c+1,c+2) + 4 just-issued in flight
    asm volatile("s_waitcnt vmcnt(8) lgkmcnt(0)" ::: "memory");
    __builtin_amdgcn_s_barrier();
    asm volatile("" ::: "memory");
    STAGE((c + 3) & 3, c + 3);      // overwrites buf[(c-1)&3]; safe: all reads done
    COMPUTE(c & 3, c);
  }
  // tail: c = 13, 14, 15 (no more staging; drain 8 -> 4 -> 0)
  asm volatile("s_waitcnt vmcnt(8) lgkmcnt(0)" ::: "memory");
  __builtin_amdgcn_s_barrier();
  asm volatile("" ::: "memory");
  COMPUTE(1, 13);
  asm volatile("s_waitcnt vmcnt(4) lgkmcnt(0)" ::: "memory");
  __builtin_amdgcn_s_barrier();
  asm volatile("" ::: "memory");
  COMPUTE(2, 14);
  asm volatile("s_waitcnt vmcnt(0) lgkmcnt(0)" ::: "memory");
  __builtin_amdgcn_s_barrier();
  asm volatile("" ::: "memory");
  COMPUTE(3, 15);

  // ---------- cross-half reduction (reuse lds[0]) ----------
  if (h) {
    float* rp = &lds[0][p * 24];
#pragma unroll
    for (int e = 0; e < E_NUM; ++e) { rp[e] = gacc[e]; rp[E_NUM + e] = sacc[e]; }
    rp[2 * E_NUM] = nrm;
  }
  asm volatile("s_waitcnt lgkmcnt(0)" ::: "memory");
  __builtin_amdgcn_s_barrier();
  asm volatile("" ::: "memory");
  if (h == 0) {
    const float* rp = &lds[0][p * 24];
#pragma unroll
    for (int e = 0; e < E_NUM; ++e) { gacc[e] += rp[e]; sacc[e] += rp[E_NUM + e]; }
    nrm += rp[2 * E_NUM];

    const float inv = 1.f / fmaxf(sqrtf(nrm), 1e-8f);
    float probs[E_NUM];
    float m = -1e30f;
#pragma unroll
    for (int e = 0; e < E_NUM; ++e) {
      float logit = gacc[e] + bg[e];
      float gate = 1.f / (1.f + __expf(-logit));
      float sim = fmaf(sacc[e] * inv, 0.5f, 0.5f);
      float sc = gate * cf[e] * sim;
      probs[e] = sc;
      m = fmaxf(m, sc);
    }
    float Z = 0.f;
#pragma unroll
    for (int e = 0; e < E_NUM; ++e) { float pe = __expf(probs[e] - m); probs[e] = pe; Z += pe; }
    const float invZ = 1.f / Z;
#pragma unroll
    for (int e = 0; e < E_NUM; ++e) probs[e] *= invZ;

    // stable top-3 (strict >, lowest index wins ties) == jax.lax.top_k
    int i0 = 0; float b0 = probs[0];
#pragma unroll
    for (int e = 1; e < E_NUM; ++e) if (probs[e] > b0) { b0 = probs[e]; i0 = e; }
    int i1 = -1; float b1 = -1.f;
#pragma unroll
    for (int e = 0; e < E_NUM; ++e) if (e != i0 && probs[e] > b1) { b1 = probs[e]; i1 = e; }
    int i2 = -1; float b2 = -1.f;
#pragma unroll
    for (int e = 0; e < E_NUM; ++e) if (e != i0 && e != i1 && probs[e] > b2) { b2 = probs[e]; i2 = e; }

    const float wnorm = 1.f / (b0 + b1 + b2);
    const size_t r = r0 + p;
    float* ow = out + r * 3;
    ow[0] = b0 * wnorm; ow[1] = b1 * wnorm; ow[2] = b2 * wnorm;
    float* oi = out + (size_t)B * 3 + r * 3;
    oi[0] = (float)i0; oi[1] = (float)i1; oi[2] = (float)i2;
    float* op = out + (size_t)B * 6 + r * E_NUM;
#pragma unroll
    for (int e = 0; e < E_NUM; ++e) op[e] = probs[e];
  }
}

extern "C" void kernel_launch(void* const* d_in, const int* in_sizes, int n_in,
                              void* d_out, int out_size, void* d_ws, size_t ws_size,
                              hipStream_t stream) {
  const float* feat  = (const float*)d_in[0];
  const float* Wp    = (const float*)d_in[1];
  const float* bp    = (const float*)d_in[2];
  const float* emb   = (const float*)d_in[3];
  const float* ef    = (const float*)d_in[4];
  const float* trust = (const float*)d_in[5];
  const float* dtv   = (const float*)d_in[6];
  float* out = (float*)d_out;

  float* pk = (float*)d_ws;                    // 128*80 = 10240 floats
  float* cf = pk + 128 * 80;                   // E_NUM
  float* bg = cf + E_NUM;                      // E_NUM

  const int B = in_sizes[0] / D_DIM;

  hipLaunchKernelGGL(pre_wg, dim3((E_NUM * D_DIM + E_NUM + 255) / 256), dim3(256),
                     0, stream, Wp, bp, emb, pk, bg);
  hipLaunchKernelGGL(pre_en, dim3(E_NUM), dim3(64), 0, stream, ef, trust, dtv, pk, cf);
  hipLaunchKernelGGL(router_main, dim3(B / ROWS_PB), dim3(256), 0, stream,
                     feat, pk, cf, bg, out, B);
}

// Round 4
// 81.162 us; speedup vs baseline: 1.9544x; 1.9544x over previous
//
#include <hip/hip_runtime.h>
#include <stdint.h>
#include <math.h>

#define D_DIM 512
#define H_DIM 256
#define E_NUM 10

typedef float f16v __attribute__((ext_vector_type(16)));

// ---------- precompute: packed weights pk[d>>2][e][gate4|sim4] + bias_g ----------
__global__ __launch_bounds__(256) void pre_wg(const float* __restrict__ Wp,
                                              const float* __restrict__ bp,
                                              const float* __restrict__ emb,
                                              float* __restrict__ pk,
                                              float* __restrict__ bg) {
  int gid = blockIdx.x * 256 + threadIdx.x;
  if (gid < E_NUM * D_DIM) {
    int d = gid / E_NUM;
    int e = gid - d * E_NUM;
    const float* wr = Wp + (size_t)d * H_DIM;
    const float* er = emb + (size_t)e * H_DIM;
    float s0 = 0.f, s1 = 0.f, s2 = 0.f, s3 = 0.f;
#pragma unroll 4
    for (int h = 0; h < H_DIM; h += 4) {
      float4 a = *(const float4*)(wr + h);
      float4 b = *(const float4*)(er + h);
      s0 = fmaf(a.x, b.x, s0); s1 = fmaf(a.y, b.y, s1);
      s2 = fmaf(a.z, b.z, s2); s3 = fmaf(a.w, b.w, s3);
    }
    pk[(size_t)(d >> 2) * 80 + e * 8 + (d & 3)] = ((s0 + s1) + (s2 + s3)) * 0.0625f;
  } else if (gid < E_NUM * D_DIM + E_NUM) {
    int e = gid - E_NUM * D_DIM;
    const float* er = emb + (size_t)e * H_DIM;
    float s = 0.f;
    for (int h = 0; h < H_DIM; ++h) s = fmaf(bp[h], er[h], s);
    bg[e] = s * 0.0625f;
  }
}

// ---------- precompute: normalized expert rows into pk sim slots + trust*stale ----------
__global__ __launch_bounds__(64) void pre_en(const float* __restrict__ ef,
                                             const float* __restrict__ trust,
                                             const float* __restrict__ dtv,
                                             float* __restrict__ pk,
                                             float* __restrict__ cf) {
  int e = blockIdx.x, l = threadIdx.x;
  const float* row = ef + (size_t)e * D_DIM;
  float s = 0.f;
#pragma unroll
  for (int j = 0; j < D_DIM / 64; ++j) { float v = row[l + 64 * j]; s = fmaf(v, v, s); }
#pragma unroll
  for (int o = 32; o; o >>= 1) s += __shfl_xor(s, o, 64);
  float inv = 1.f / fmaxf(sqrtf(s), 1e-8f);
#pragma unroll
  for (int j = 0; j < D_DIM / 64; ++j) {
    int d = l + 64 * j;
    pk[(size_t)(d >> 2) * 80 + e * 8 + 4 + (d & 3)] = row[d] * inv;
  }
  if (l == 0) cf[e] = trust[e] * expf(-0.001f * dtv[e]);
}

// weight selector: i is compile-time under full unroll -> folds to a register
#define WV(i) ((i) < 16 ? w0[(i) & 15] : (i) < 32 ? w1[(i) & 15] : \
               (i) < 48 ? w2[(i) & 15] : (i) < 64 ? w3[(i) & 15] : w4[(i) & 15])

// ---------- main: quarter-row per thread (quarter = wave), SGPR weights ----------
__global__ __launch_bounds__(256, 4) void router_main(
    const float* __restrict__ feat, const float* __restrict__ pk,
    const float* __restrict__ cf, const float* __restrict__ bg,
    float* __restrict__ out, int B) {
  __shared__ float red[3 * 64 * 23];
  const int t = threadIdx.x;
  const int l = t & 63;
  const int w = __builtin_amdgcn_readfirstlane(t >> 6);   // wave id = d-quarter
  const size_t row = (size_t)blockIdx.x * 64 + l;
  const float* gp = feat + row * D_DIM + w * 128;
  const float* wq = pk + (size_t)w * 32 * 80;             // wave-uniform

  float acc[21];                                          // 10 gate, 10 sim, nrm
#pragma unroll
  for (int i = 0; i < 21; ++i) acc[i] = 0.f;

  float4 fvA[8], fvB[8];
#pragma unroll
  for (int j = 0; j < 8; ++j) fvA[j] = *(const float4*)(gp + j * 4);

#pragma unroll
  for (int it = 0; it < 4; ++it) {
    float4* cur = (it & 1) ? fvB : fvA;
    float4* nxt = (it & 1) ? fvA : fvB;
    if (it < 3) {
#pragma unroll
      for (int j = 0; j < 8; ++j) nxt[j] = *(const float4*)(gp + (it + 1) * 32 + j * 4);
    }
#pragma unroll
    for (int sub = 0; sub < 8; ++sub) {
      f16v w0, w1, w2, w3, w4;
      const float* wp = wq + (it * 8 + sub) * 80;         // wave-uniform
      asm volatile(
          "s_load_dwordx16 %0, %5, 0x0\n"
          "s_load_dwordx16 %1, %5, 0x40\n"
          "s_load_dwordx16 %2, %5, 0x80\n"
          "s_load_dwordx16 %3, %5, 0xc0\n"
          "s_load_dwordx16 %4, %5, 0x100\n"
          "s_waitcnt lgkmcnt(0)"
          : "=&s"(w0), "=&s"(w1), "=&s"(w2), "=&s"(w3), "=&s"(w4)
          : "s"(wp));
      float4 f = cur[sub];
#pragma unroll
      for (int e = 0; e < E_NUM; ++e) {
        const int b = e * 8;
        float a = acc[e];
        a = fmaf(f.x, WV(b + 0), a); a = fmaf(f.y, WV(b + 1), a);
        a = fmaf(f.z, WV(b + 2), a); a = fmaf(f.w, WV(b + 3), a);
        acc[e] = a;
        float s2 = acc[10 + e];
        s2 = fmaf(f.x, WV(b + 4), s2); s2 = fmaf(f.y, WV(b + 5), s2);
        s2 = fmaf(f.z, WV(b + 6), s2); s2 = fmaf(f.w, WV(b + 7), s2);
        acc[10 + e] = s2;
      }
      float n = acc[20];
      n = fmaf(f.x, f.x, n); n = fmaf(f.y, f.y, n);
      n = fmaf(f.z, f.z, n); n = fmaf(f.w, f.w, n);
      acc[20] = n;
    }
  }

  // ---------- cross-wave reduction ----------
  if (w) {
    float* rp = &red[((w - 1) * 64 + l) * 23];
#pragma unroll
    for (int i = 0; i < 21; ++i) rp[i] = acc[i];
  }
  __syncthreads();
  if (w == 0) {
#pragma unroll
    for (int s = 0; s < 3; ++s) {
      const float* rp = &red[(s * 64 + l) * 23];
#pragma unroll
      for (int i = 0; i < 21; ++i) acc[i] += rp[i];
    }

    const float inv = 1.f / fmaxf(sqrtf(acc[20]), 1e-8f);
    float probs[E_NUM];
    float m = -1e30f;
#pragma unroll
    for (int e = 0; e < E_NUM; ++e) {
      float logit = acc[e] + bg[e];
      float gate = 1.f / (1.f + __expf(-logit));
      float sim = fmaf(acc[10 + e] * inv, 0.5f, 0.5f);
      float sc = gate * cf[e] * sim;
      probs[e] = sc;
      m = fmaxf(m, sc);
    }
    float Z = 0.f;
#pragma unroll
    for (int e = 0; e < E_NUM; ++e) { float pe = __expf(probs[e] - m); probs[e] = pe; Z += pe; }
    const float invZ = 1.f / Z;
#pragma unroll
    for (int e = 0; e < E_NUM; ++e) probs[e] *= invZ;

    // stable top-3 (strict >, lowest index wins ties) == jax.lax.top_k
    int i0 = 0; float b0 = probs[0];
#pragma unroll
    for (int e = 1; e < E_NUM; ++e) if (probs[e] > b0) { b0 = probs[e]; i0 = e; }
    int i1 = -1; float b1 = -1.f;
#pragma unroll
    for (int e = 0; e < E_NUM; ++e) if (e != i0 && probs[e] > b1) { b1 = probs[e]; i1 = e; }
    int i2 = -1; float b2 = -1.f;
#pragma unroll
    for (int e = 0; e < E_NUM; ++e) if (e != i0 && e != i1 && probs[e] > b2) { b2 = probs[e]; i2 = e; }

    const float wnorm = 1.f / (b0 + b1 + b2);
    float* ow = out + row * 3;
    ow[0] = b0 * wnorm; ow[1] = b1 * wnorm; ow[2] = b2 * wnorm;
    float* oi = out + (size_t)B * 3 + row * 3;
    oi[0] = (float)i0; oi[1] = (float)i1; oi[2] = (float)i2;
    float* op = out + (size_t)B * 6 + row * E_NUM;
#pragma unroll
    for (int e = 0; e < E_NUM; ++e) op[e] = probs[e];
  }
}

extern "C" void kernel_launch(void* const* d_in, const int* in_sizes, int n_in,
                              void* d_out, int out_size, void* d_ws, size_t ws_size,
                              hipStream_t stream) {
  const float* feat  = (const float*)d_in[0];
  const float* Wp    = (const float*)d_in[1];
  const float* bp    = (const float*)d_in[2];
  const float* emb   = (const float*)d_in[3];
  const float* ef    = (const float*)d_in[4];
  const float* trust = (const float*)d_in[5];
  const float* dtv   = (const float*)d_in[6];
  float* out = (float*)d_out;

  float* pk = (float*)d_ws;                    // 128*80 = 10240 floats
  float* cf = pk + 128 * 80;                   // E_NUM
  float* bg = cf + E_NUM;                      // E_NUM

  const int B = in_sizes[0] / D_DIM;

  hipLaunchKernelGGL(pre_wg, dim3((E_NUM * D_DIM + E_NUM + 255) / 256), dim3(256),
                     0, stream, Wp, bp, emb, pk, bg);
  hipLaunchKernelGGL(pre_en, dim3(E_NUM), dim3(64), 0, stream, ef, trust, dtv, pk, cf);
  hipLaunchKernelGGL(router_main, dim3(B / 64), dim3(256), 0, stream,
                     feat, pk, cf, bg, out, B);
}

// Round 5
// 73.681 us; speedup vs baseline: 2.1529x; 1.1015x over previous
//
#include <hip/hip_runtime.h>
#include <stdint.h>
#include <math.h>

#define D_DIM 512
#define H_DIM 256
#define E_NUM 10

typedef float f16v __attribute__((ext_vector_type(16)));
typedef float f2 __attribute__((ext_vector_type(2)));

// ---------- precompute: packed weights pk[d][gate e0..9 | sim e0..9] + bias_g ----------
__global__ __launch_bounds__(256) void pre_wg(const float* __restrict__ Wp,
                                              const float* __restrict__ bp,
                                              const float* __restrict__ emb,
                                              float* __restrict__ pk,
                                              float* __restrict__ bg) {
  int gid = blockIdx.x * 256 + threadIdx.x;
  if (gid < E_NUM * D_DIM) {
    int d = gid / E_NUM;
    int e = gid - d * E_NUM;
    const float* wr = Wp + (size_t)d * H_DIM;
    const float* er = emb + (size_t)e * H_DIM;
    float s0 = 0.f, s1 = 0.f, s2 = 0.f, s3 = 0.f;
#pragma unroll 4
    for (int h = 0; h < H_DIM; h += 4) {
      float4 a = *(const float4*)(wr + h);
      float4 b = *(const float4*)(er + h);
      s0 = fmaf(a.x, b.x, s0); s1 = fmaf(a.y, b.y, s1);
      s2 = fmaf(a.z, b.z, s2); s3 = fmaf(a.w, b.w, s3);
    }
    pk[(size_t)d * 20 + e] = ((s0 + s1) + (s2 + s3)) * 0.0625f;
  } else if (gid < E_NUM * D_DIM + E_NUM) {
    int e = gid - E_NUM * D_DIM;
    const float* er = emb + (size_t)e * H_DIM;
    float s = 0.f;
    for (int h = 0; h < H_DIM; ++h) s = fmaf(bp[h], er[h], s);
    bg[e] = s * 0.0625f;
  }
}

// ---------- precompute: normalized expert rows into pk sim slots + trust*stale ----------
__global__ __launch_bounds__(64) void pre_en(const float* __restrict__ ef,
                                             const float* __restrict__ trust,
                                             const float* __restrict__ dtv,
                                             float* __restrict__ pk,
                                             float* __restrict__ cf) {
  int e = blockIdx.x, l = threadIdx.x;
  const float* row = ef + (size_t)e * D_DIM;
  float s = 0.f;
#pragma unroll
  for (int j = 0; j < D_DIM / 64; ++j) { float v = row[l + 64 * j]; s = fmaf(v, v, s); }
#pragma unroll
  for (int o = 32; o; o >>= 1) s += __shfl_xor(s, o, 64);
  float inv = 1.f / fmaxf(sqrtf(s), 1e-8f);
#pragma unroll
  for (int j = 0; j < D_DIM / 64; ++j) {
    int d = l + 64 * j;
    pk[(size_t)d * 20 + 10 + e] = row[d] * inv;
  }
  if (l == 0) cf[e] = trust[e] * expf(-0.001f * dtv[e]);
}

// element i (0..79) of the 5 SGPR x16 vectors; i compile-time under unroll
#define WVx(i) ((i) < 16 ? w0[(i) & 15] : (i) < 32 ? w1[(i) & 15] : \
                (i) < 48 ? w2[(i) & 15] : (i) < 64 ? w3[(i) & 15] : w4[(i) & 15])

// ---------- main: quarter-row per thread (quarter = wave), SGPR weights, pk-fma ----------
__global__ __launch_bounds__(256, 6) void router_main(
    const float* __restrict__ feat, const float* __restrict__ pk,
    const float* __restrict__ cf, const float* __restrict__ bg,
    float* __restrict__ out, int B) {
  __shared__ float red[3 * 64 * 23];
  const int t = threadIdx.x;
  const int l = t & 63;
  const int w = __builtin_amdgcn_readfirstlane(t >> 6);   // wave id = d-quarter
  const size_t row = (size_t)blockIdx.x * 64 + l;
  const float* gp = feat + row * D_DIM + w * 128;
  const float* wq = pk + (size_t)w * 128 * 20;            // wave-uniform

  f2 ag[5], as_[5], n2;                                   // paired accumulators
#pragma unroll
  for (int i = 0; i < 5; ++i) { ag[i] = f2{0.f, 0.f}; as_[i] = f2{0.f, 0.f}; }
  n2 = f2{0.f, 0.f};

  float4 fvA[4], fvB[4];
#pragma unroll
  for (int j = 0; j < 4; ++j) fvA[j] = *(const float4*)(gp + j * 4);

#pragma unroll
  for (int it = 0; it < 8; ++it) {
    float4* cur = (it & 1) ? fvB : fvA;
    float4* nxt = (it & 1) ? fvA : fvB;
    if (it < 7) {
#pragma unroll
      for (int j = 0; j < 4; ++j) nxt[j] = *(const float4*)(gp + (it + 1) * 16 + j * 4);
    }
#pragma unroll
    for (int sub = 0; sub < 4; ++sub) {
      f16v w0, w1, w2, w3, w4;
      const float* wp = wq + (it * 4 + sub) * 80;         // wave-uniform
      asm volatile(
          "s_load_dwordx16 %0, %5, 0x0\n"
          "s_load_dwordx16 %1, %5, 0x40\n"
          "s_load_dwordx16 %2, %5, 0x80\n"
          "s_load_dwordx16 %3, %5, 0xc0\n"
          "s_load_dwordx16 %4, %5, 0x100\n"
          "s_waitcnt lgkmcnt(0)"
          : "=&s"(w0), "=&s"(w1), "=&s"(w2), "=&s"(w3), "=&s"(w4)
          : "s"(wp));
      float4 f = cur[sub];
#pragma unroll
      for (int q = 0; q < 4; ++q) {
        const float fq = (q == 0) ? f.x : (q == 1) ? f.y : (q == 2) ? f.z : f.w;
        const f2 fq2 = {fq, fq};
#pragma unroll
        for (int j = 0; j < 5; ++j) {
          const int bgi = q * 20 + 2 * j;
          f2 wg2 = {WVx(bgi), WVx(bgi + 1)};
          ag[j] = __builtin_elementwise_fma(fq2, wg2, ag[j]);
        }
#pragma unroll
        for (int j = 0; j < 5; ++j) {
          const int bsi = q * 20 + 10 + 2 * j;
          f2 ws2 = {WVx(bsi), WVx(bsi + 1)};
          as_[j] = __builtin_elementwise_fma(fq2, ws2, as_[j]);
        }
      }
      f2 p0 = {f.x, f.y}, p1 = {f.z, f.w};
      n2 = __builtin_elementwise_fma(p0, p0, n2);
      n2 = __builtin_elementwise_fma(p1, p1, n2);
    }
  }

  float acc[21];
#pragma unroll
  for (int e = 0; e < E_NUM; ++e) { acc[e] = ag[e >> 1][e & 1]; acc[10 + e] = as_[e >> 1][e & 1]; }
  acc[20] = n2.x + n2.y;

  // ---------- cross-wave reduction ----------
  if (w) {
    float* rp = &red[((w - 1) * 64 + l) * 23];
#pragma unroll
    for (int i = 0; i < 21; ++i) rp[i] = acc[i];
  }
  __syncthreads();
  if (w == 0) {
#pragma unroll
    for (int s = 0; s < 3; ++s) {
      const float* rp = &red[(s * 64 + l) * 23];
#pragma unroll
      for (int i = 0; i < 21; ++i) acc[i] += rp[i];
    }

    const float inv = 1.f / fmaxf(sqrtf(acc[20]), 1e-8f);
    float probs[E_NUM];
    float m = -1e30f;
#pragma unroll
    for (int e = 0; e < E_NUM; ++e) {
      float logit = acc[e] + bg[e];
      float gate = 1.f / (1.f + __expf(-logit));
      float sim = fmaf(acc[10 + e] * inv, 0.5f, 0.5f);
      float sc = gate * cf[e] * sim;
      probs[e] = sc;
      m = fmaxf(m, sc);
    }
    float Z = 0.f;
#pragma unroll
    for (int e = 0; e < E_NUM; ++e) { float pe = __expf(probs[e] - m); probs[e] = pe; Z += pe; }
    const float invZ = 1.f / Z;
#pragma unroll
    for (int e = 0; e < E_NUM; ++e) probs[e] *= invZ;

    // stable top-3 (strict >, lowest index wins ties) == jax.lax.top_k
    int i0 = 0; float b0 = probs[0];
#pragma unroll
    for (int e = 1; e < E_NUM; ++e) if (probs[e] > b0) { b0 = probs[e]; i0 = e; }
    int i1 = -1; float b1 = -1.f;
#pragma unroll
    for (int e = 0; e < E_NUM; ++e) if (e != i0 && probs[e] > b1) { b1 = probs[e]; i1 = e; }
    int i2 = -1; float b2 = -1.f;
#pragma unroll
    for (int e = 0; e < E_NUM; ++e) if (e != i0 && e != i1 && probs[e] > b2) { b2 = probs[e]; i2 = e; }

    const float wnorm = 1.f / (b0 + b1 + b2);
    float* ow = out + row * 3;
    ow[0] = b0 * wnorm; ow[1] = b1 * wnorm; ow[2] = b2 * wnorm;
    float* oi = out + (size_t)B * 3 + row * 3;
    oi[0] = (float)i0; oi[1] = (float)i1; oi[2] = (float)i2;
    float* op = out + (size_t)B * 6 + row * E_NUM;
#pragma unroll
    for (int e = 0; e < E_NUM; ++e) op[e] = probs[e];
  }
}

extern "C" void kernel_launch(void* const* d_in, const int* in_sizes, int n_in,
                              void* d_out, int out_size, void* d_ws, size_t ws_size,
                              hipStream_t stream) {
  const float* feat  = (const float*)d_in[0];
  const float* Wp    = (const float*)d_in[1];
  const float* bp    = (const float*)d_in[2];
  const float* emb   = (const float*)d_in[3];
  const float* ef    = (const float*)d_in[4];
  const float* trust = (const float*)d_in[5];
  const float* dtv   = (const float*)d_in[6];
  float* out = (float*)d_out;

  float* pk = (float*)d_ws;                    // 512*20 = 10240 floats
  float* cf = pk + D_DIM * 20;                 // E_NUM
  float* bg = cf + E_NUM;                      // E_NUM

  const int B = in_sizes[0] / D_DIM;

  hipLaunchKernelGGL(pre_wg, dim3((E_NUM * D_DIM + E_NUM + 255) / 256), dim3(256),
                     0, stream, Wp, bp, emb, pk, bg);
  hipLaunchKernelGGL(pre_en, dim3(E_NUM), dim3(64), 0, stream, ef, trust, dtv, pk, cf);
  hipLaunchKernelGGL(router_main, dim3(B / 64), dim3(256), 0, stream,
                     feat, pk, cf, bg, out, B);
}